// Round 1
// baseline (537.011 us; speedup 1.0000x reference)
//
#include <hip/hip_runtime.h>

// Problem constants (from reference):
//   x: [16, 128, 128, 128] fp32 ; pixel_shuffle(2) -> [16, 32, 256, 256]
//   4x4 FIR (outer([1,3,3,1]) / 64), pad=2 -> out [16, 32, 257, 257] fp32
constexpr int Bn  = 16;
constexpr int CIN = 128;
constexpr int Hn  = 128;
constexpr int Wn  = 128;
constexpr int Cc  = 32;          // CIN / 4 channels after shuffle
constexpr int SH  = 2 * Hn;      // 256 shuffled height
constexpr int SW  = 2 * Wn;      // 256 shuffled width
constexpr int OH  = SH + 1;      // 257
constexpr int OW  = SW + 1;      // 257
constexpr int TOTAL = Bn * Cc * OH * OW;   // 33,817,088 (< 2^31)

__global__ __launch_bounds__(256) void upsamp_fir_kernel(
    const float* __restrict__ x,
    const float* __restrict__ k4,   // 4x4 kernel, row-major
    float* __restrict__ out)
{
    int tid = blockIdx.x * 256 + threadIdx.x;
    if (tid >= TOTAL) return;

    int ow   = tid % OW;
    int rest = tid / OW;
    int oh   = rest % OH;
    int bc   = rest / OH;          // b*Cc + c ; channel base in x = bc*4

    // Base of the 4 sub-channel planes for this (b, c):
    const float* xp = x + (size_t)bc * 4 * Hn * Wn;

    // True convolution => flipped taps (numerically a no-op for this
    // symmetric kernel, but correct in general). Uniform scalar loads.
    float wt[4][4];
#pragma unroll
    for (int i = 0; i < 4; ++i)
#pragma unroll
        for (int j = 0; j < 4; ++j)
            wt[i][j] = k4[(3 - i) * 4 + (3 - j)];

    float acc = 0.f;
#pragma unroll
    for (int i = 0; i < 4; ++i) {
        int h = oh + i - 2;                       // shuffled-space row
        if ((unsigned)h >= (unsigned)SH) continue; // zero pad
        int hi = h >> 1;
        int r1 = h & 1;
        // plane (2*r1 + r2): add r2*Hn*Wn per tap below
        const float* prow = xp + ((size_t)(2 * r1) * Hn + hi) * Wn;
#pragma unroll
        for (int j = 0; j < 4; ++j) {
            int w = ow + j - 2;                   // shuffled-space col
            if ((unsigned)w >= (unsigned)SW) continue;
            int wi = w >> 1;
            int r2 = w & 1;
            acc += wt[i][j] * prow[(size_t)r2 * Hn * Wn + wi];
        }
    }
    out[tid] = acc;
}

extern "C" void kernel_launch(void* const* d_in, const int* in_sizes, int n_in,
                              void* d_out, int out_size, void* d_ws, size_t ws_size,
                              hipStream_t stream)
{
    const float* x  = (const float*)d_in[0];
    const float* k4 = (const float*)d_in[1];
    float* out      = (float*)d_out;

    int blocks = (TOTAL + 255) / 256;
    upsamp_fir_kernel<<<dim3(blocks), dim3(256), 0, stream>>>(x, k4, out);
}

// Round 2
// 341.484 us; speedup vs baseline: 1.5726x; 1.5726x over previous
//
#include <hip/hip_runtime.h>

// x: [16, 128, 128, 128] fp32 ; pixel_shuffle(2) -> [16, 32, 256, 256]
// 4x4 separable FIR (outer([1,3,3,1])/64), pad=2 -> out [16, 32, 257, 257]
//
// Fused + separable: never materialize the shuffle. For output column ow,
// the horizontal 4-tap over shuffled row h reads 4 elements from base planes
// (2*(h&1) + {0,1}) at base row h>>1, columns {x0-1, x0} (parity-dependent).
// Column offsets + boundary-masked weights are loop-invariant per thread.
// Vertical 4-tap = rolling window of 4 horizontal results V(h).
constexpr int Bn = 16;
constexpr int Hn = 128;
constexpr int Wn = 128;
constexpr int Cc = 32;           // channels after shuffle
constexpr int SH = 2 * Hn;       // 256
constexpr int SW = 2 * Wn;       // 256
constexpr int OH = SH + 1;       // 257
constexpr int OW = SW + 1;       // 257
constexpr int HW = Hn * Wn;      // plane stride (floats)
constexpr int NCOL = Bn * Cc * OW;          // 131584 (bc, ow) columns
constexpr int TY = 32;                      // output rows per thread strip
constexpr int NTILE = (OH + TY - 1) / TY;   // 9

__global__ __launch_bounds__(256) void upsamp_fir_sep(
    const float* __restrict__ x,
    const float* __restrict__ k4,    // 4x4 kernel, row-major
    float* __restrict__ out)
{
    int col = blockIdx.x * 256 + threadIdx.x;
    if (col >= NCOL) return;
    int ow = col % OW;
    int bc = col / OW;
    const float* xp = x + (size_t)bc * 4 * HW;

    // Recover separable taps from the rank-1, sum-1 kernel:
    //   fv[i] = row-sum, fh[j] = col-sum  =>  fv[i]*fh[j] == k4[i][j] exactly.
    float fh[4], fv[4];
#pragma unroll
    for (int j = 0; j < 4; ++j)
        fh[j] = k4[0*4+j] + k4[1*4+j] + k4[2*4+j] + k4[3*4+j];
#pragma unroll
    for (int i = 0; i < 4; ++i)
        fv[i] = k4[i*4+0] + k4[i*4+1] + k4[i*4+2] + k4[i*4+3];
    // True convolution => flipped taps (no-op for symmetric filter).
    const float fhf[4] = {fh[3], fh[2], fh[1], fh[0]};
    const float fvf[4] = {fv[3], fv[2], fv[1], fv[0]};

    // Per-thread horizontal tap table: dword offset within the r1-pair base
    // and boundary-masked weight. Loop-invariant over h.
    int   off[4];
    float wgt[4];
#pragma unroll
    for (int j = 0; j < 4; ++j) {
        int w = ow - 2 + j;                       // shuffled-space col
        bool valid = (unsigned)w < (unsigned)SW;  // zero pad
        int wi = w >> 1;                          // arith shift ok for w<0
        wi = wi < 0 ? 0 : (wi > Wn - 1 ? Wn - 1 : wi);
        int r2 = w & 1;
        off[j] = r2 * HW + wi;
        wgt[j] = valid ? fhf[j] : 0.f;
    }

    const int oh0 = blockIdx.y * TY;

    // Horizontal FIR on shuffled row h (4 loads + 4 FMA); 0 outside pad.
    auto V = [&](int h) -> float {
        if ((unsigned)h >= (unsigned)SH) return 0.f;
        const float* base = xp + (size_t)(2 * (h & 1)) * HW + (size_t)(h >> 1) * Wn;
        return wgt[0] * base[off[0]] + wgt[1] * base[off[1]]
             + wgt[2] * base[off[2]] + wgt[3] * base[off[3]];
    };

    float v0 = V(oh0 - 2);
    float v1 = V(oh0 - 1);
    float v2 = V(oh0);

    float* op = out + ((size_t)bc * OH + oh0) * OW + ow;
#pragma unroll 4
    for (int t = 0; t < TY; ++t) {
        int oh = oh0 + t;
        if (oh >= OH) break;                      // uniform across grid-y tile
        float v3 = V(oh + 1);
        op[(size_t)t * OW] = fvf[0] * v0 + fvf[1] * v1 + fvf[2] * v2 + fvf[3] * v3;
        v0 = v1; v1 = v2; v2 = v3;
    }
}

extern "C" void kernel_launch(void* const* d_in, const int* in_sizes, int n_in,
                              void* d_out, int out_size, void* d_ws, size_t ws_size,
                              hipStream_t stream)
{
    const float* x  = (const float*)d_in[0];
    const float* k4 = (const float*)d_in[1];
    float* out      = (float*)d_out;

    dim3 grid((NCOL + 255) / 256, NTILE, 1);
    upsamp_fir_sep<<<grid, dim3(256), 0, stream>>>(x, k4, out);
}

// Round 3
// 285.800 us; speedup vs baseline: 1.8790x; 1.1948x over previous
//
#include <hip/hip_runtime.h>

// x: [16,128,128,128] fp32 ; pixel_shuffle(2) -> [16,32,256,256]
// 4x4 separable FIR (outer([1,3,3,1])/64), pad=2 -> out [16,32,257,257]
//
// R2: 8 outputs per thread along w. The 11-tap shuffled-col window for
// outputs 8g..8g+7 needs even-parity dwords wi=4g-1..4g+4 (6) and odd-parity
// dwords wi=4g-1..4g+3 (5): one aligned float4 + 2 scalars (even plane) and
// one aligned float4 + 1 scalar (odd plane) per shuffled row. Boundary
// zero-pad folded into per-thread loop-invariant value masks. Vertical 4-tap
// via rolling window of 8-wide horizontal results.
constexpr int Bn = 16;
constexpr int Hn = 128;
constexpr int Wn = 128;
constexpr int Cc = 32;
constexpr int SH = 2 * Hn;   // 256
constexpr int SW = 2 * Wn;   // 256
constexpr int OH = SH + 1;   // 257
constexpr int OW = SW + 1;   // 257
constexpr int HW = Hn * Wn;  // plane stride
constexpr int NG = 33;       // ceil(257/8) column groups of 8 outputs
constexpr int TY = 16;       // output rows per thread
constexpr int NSTRIP = (OH + TY - 1) / TY;        // 17
constexpr int NTHREADS = Bn * Cc * NG;            // 16896 = 66 * 256

__global__ __launch_bounds__(256) void upsamp_fir8(
    const float* __restrict__ x,
    const float* __restrict__ k4,
    float* __restrict__ out)
{
    const int tid = blockIdx.x * 256 + threadIdx.x;   // < 16896 exactly
    const int g  = tid % NG;
    const int bc = tid / NG;
    const float* xp = x + (size_t)bc * 4 * HW;

    // Separable taps from the rank-1, sum-1 kernel (exact: powers-of-two
    // scaled small ints), flipped for true convolution.
    float fh[4], fv[4];
#pragma unroll
    for (int j = 0; j < 4; ++j) fh[j] = k4[j] + k4[4+j] + k4[8+j] + k4[12+j];
#pragma unroll
    for (int i = 0; i < 4; ++i) fv[i] = k4[4*i] + k4[4*i+1] + k4[4*i+2] + k4[4*i+3];
    const float h0 = fh[3], h1 = fh[2], h2 = fh[1], h3 = fh[0];
    const float g0 = fv[3], g1 = fv[2], g2 = fv[1], g3 = fv[0];

    // Loop-invariant clamped addresses + boundary value masks.
    const int ci  = 4 * g;
    const int aM1 = ci - 1 < 0 ? 0 : ci - 1;          // wi = 4g-1 (E[0], O[0])
    const int a4  = ci > Wn - 4 ? Wn - 4 : ci;        // aligned float4 base
    const int aP4 = ci + 4 > Wn - 1 ? Wn - 1 : ci + 4;// wi = 4g+4 (E[5])
    float mE[6], mO[5];
#pragma unroll
    for (int i = 0; i < 6; ++i) { int w = 8*g - 2 + 2*i; mE[i] = (unsigned)w < (unsigned)SW ? 1.f : 0.f; }
#pragma unroll
    for (int i = 0; i < 5; ++i) { int w = 8*g - 1 + 2*i; mO[i] = (unsigned)w < (unsigned)SW ? 1.f : 0.f; }

    // Horizontal FIR for 8 outputs on shuffled row h.
    auto loadrow = [&](int h, float* V) {
        if ((unsigned)h >= (unsigned)SH) {
#pragma unroll
            for (int k = 0; k < 8; ++k) V[k] = 0.f;
            return;
        }
        const float* be = xp + (size_t)(2 * (h & 1)) * HW + (size_t)(h >> 1) * Wn;
        const float* bo = be + HW;
        float E[6], O[5];
        E[0] = be[aM1];
        float4 e4 = *(const float4*)(be + a4);   // 16B aligned: be,a4 mult of 4 dwords
        E[1] = e4.x; E[2] = e4.y; E[3] = e4.z; E[4] = e4.w;
        E[5] = be[aP4];
        O[0] = bo[aM1];
        float4 o4 = *(const float4*)(bo + a4);
        O[1] = o4.x; O[2] = o4.y; O[3] = o4.z; O[4] = o4.w;
#pragma unroll
        for (int i = 0; i < 6; ++i) E[i] *= mE[i];
#pragma unroll
        for (int i = 0; i < 5; ++i) O[i] *= mO[i];
#pragma unroll
        for (int k = 0; k < 8; k += 2) {
            int i = k >> 1;
            V[k]   = h0*E[i] + h1*O[i]   + h2*E[i+1] + h3*O[i+1];
            V[k+1] = h0*O[i] + h1*E[i+1] + h2*O[i+1] + h3*E[i+2];
        }
    };

    const int oh0 = blockIdx.y * TY;
    float va[8], vb[8], vc[8], vd[8];
    loadrow(oh0 - 2, va);
    loadrow(oh0 - 1, vb);
    loadrow(oh0,     vc);

    float* op = out + ((size_t)bc * OH + oh0) * OW + 8 * g;
    const int tmax = (OH - oh0) < TY ? (OH - oh0) : TY;
#pragma unroll 4
    for (int t = 0; t < tmax; ++t) {
        loadrow(oh0 + t + 1, vd);
        float o[8];
#pragma unroll
        for (int k = 0; k < 8; ++k)
            o[k] = g0*va[k] + g1*vb[k] + g2*vc[k] + g3*vd[k];
        float* p = op + (size_t)t * OW;
        if (g < NG - 1) {
#pragma unroll
            for (int k = 0; k < 8; ++k) p[k] = o[k];   // OW=257: rows only 4B aligned
        } else {
            p[0] = o[0];                               // ow = 256 only
        }
#pragma unroll
        for (int k = 0; k < 8; ++k) { va[k] = vb[k]; vb[k] = vc[k]; vc[k] = vd[k]; }
    }
}

extern "C" void kernel_launch(void* const* d_in, const int* in_sizes, int n_in,
                              void* d_out, int out_size, void* d_ws, size_t ws_size,
                              hipStream_t stream)
{
    const float* x  = (const float*)d_in[0];
    const float* k4 = (const float*)d_in[1];
    float* out      = (float*)d_out;

    dim3 grid(NTHREADS / 256, NSTRIP, 1);
    upsamp_fir8<<<grid, dim3(256), 0, stream>>>(x, k4, out);
}